// Round 1
// baseline (1352.144 us; speedup 1.0000x reference)
//
#include <hip/hip_runtime.h>
#include <hip/hip_bf16.h>
#include <math.h>

// Problem constants (from reference)
#define S_   3
#define B_   32
#define C_   512
#define E_   256      // INPUT_DIM
#define H_   512      // HIDDEN_DIM
#define P_   256      // PRED_LEN
#define T_   49152    // S*B*C tokens (expert weights shared across scales -> flatten)
#define TBC_ 16384    // B*C

typedef __attribute__((ext_vector_type(8))) short v_s16x8;  // 8 bf16 (4 VGPR)
typedef __attribute__((ext_vector_type(4))) float v_f32x4;  // MFMA accumulator

__device__ __forceinline__ float gelu_f(float x) {
  // exact gelu (approximate=False): 0.5*x*(1+erf(x/sqrt(2)))
  return 0.5f * x * (1.0f + erff(x * 0.70710678118654752440f));
}

__device__ __forceinline__ void gload_lds16(const void* g, void* l) {
  // async global->LDS, 16B per lane; LDS dest = wave-uniform base + lane*16
  __builtin_amdgcn_global_load_lds((const __attribute__((address_space(1))) void*)g,
                                   (__attribute__((address_space(3))) void*)l, 16, 0, 0);
}

// ---------------------------------------------------------------------------
// Fused router: w = softmax(gelu(x@rw1+rb1)@rw2+rb2); top-2 of locals;
// outputs wtok[t][8] = {w0, w1, masked local weights}, entropy partial sum.
// fp32 throughout (top-k tie sensitivity).
// Block: 256 threads, 64 tokens. LDS ~100KB.
// ---------------------------------------------------------------------------
__global__ __launch_bounds__(256) void router_kernel(
    const float* __restrict__ x,   // [T,256]
    const float* __restrict__ w1,  // [256,512]
    const float* __restrict__ b1,  // [512]
    const float* __restrict__ w2,  // [512,8]
    const float* __restrict__ b2,  // [8]
    float* __restrict__ wtok,      // [T,8]
    float* __restrict__ entp)      // [1] accumulates sum_t sum_e w*log(w+1e-8)
{
  __shared__ float xs[256][64];   // x transposed [k][t], 4-float-slot XOR swizzle
  __shared__ float ws1[64][68];   // weight k-panel [k][c], padded
  __shared__ float ws2[512][8];   // rw2
  __shared__ float slog[64][8];   // logit accumulation

  const int tid  = threadIdx.x;
  const int tblk = blockIdx.x * 64;

  // stage x (coalesced 1KB rows), write transposed with slot swizzle
  {
    const int lane6 = tid & 63;
    const int tq    = tid >> 6;
    for (int it = 0; it < 16; ++it) {
      int t  = it * 4 + tq;
      int k0 = lane6 * 4;
      float4 v = *(const float4*)&x[(size_t)(tblk + t) * 256 + k0];
      float vv[4] = {v.x, v.y, v.z, v.w};
#pragma unroll
      for (int i = 0; i < 4; ++i) {
        int k = k0 + i;
        int slot = (t >> 2) ^ ((k >> 2) & 15);
        xs[k][slot * 4 + (t & 3)] = vv[i];
      }
    }
  }
  for (int i = tid; i < 4096; i += 256) ws2[i >> 3][i & 7] = w2[i];
  if (tid < 64) {
#pragma unroll
    for (int e = 0; e < 8; ++e) slog[tid][e] = 0.f;
  }

  const int tg = tid & 15;   // token group: tokens tg*4..+3
  const int cg = tid >> 4;   // col group within 64-col chunk
  const int t0 = tg * 4;
  float lacc[4][8];
#pragma unroll
  for (int i = 0; i < 4; ++i)
#pragma unroll
    for (int e = 0; e < 8; ++e) lacc[i][e] = 0.f;

  for (int ch = 0; ch < 8; ++ch) {     // 8 chunks of 64 hidden cols
    float h[4][4];
#pragma unroll
    for (int i = 0; i < 4; ++i)
#pragma unroll
      for (int j = 0; j < 4; ++j) h[i][j] = 0.f;
    for (int kp = 0; kp < 4; ++kp) {   // k panels of 64
      __syncthreads();                 // previous panel fully consumed / initial stage visible
      for (int i = tid; i < 1024; i += 256) {   // 64 rows x 16 float4
        int r = i >> 4, c4 = (i & 15) << 2;
        *(float4*)&ws1[r][c4] = *(const float4*)&w1[(size_t)(kp * 64 + r) * 512 + ch * 64 + c4];
      }
      __syncthreads();
#pragma unroll 8
      for (int k = 0; k < 64; ++k) {
        int kk = kp * 64 + k;
        int slot = tg ^ ((kk >> 2) & 15);
        float4 a = *(const float4*)&xs[kk][slot * 4];
        float4 w = *(const float4*)&ws1[k][cg * 4];
        float av[4] = {a.x, a.y, a.z, a.w};
        float wv[4] = {w.x, w.y, w.z, w.w};
#pragma unroll
        for (int tt = 0; tt < 4; ++tt)
#pragma unroll
          for (int cc = 0; cc < 4; ++cc) h[tt][cc] += av[tt] * wv[cc];
      }
    }
    // gelu + logit partials
#pragma unroll
    for (int cc = 0; cc < 4; ++cc) {
      int col = ch * 64 + cg * 4 + cc;
      float bv = b1[col];
#pragma unroll
      for (int tt = 0; tt < 4; ++tt) {
        float g = gelu_f(h[tt][cc] + bv);
#pragma unroll
        for (int e = 0; e < 8; ++e) lacc[tt][e] += g * ws2[col][e];
      }
    }
  }
#pragma unroll
  for (int tt = 0; tt < 4; ++tt)
#pragma unroll
    for (int e = 0; e < 8; ++e) atomicAdd(&slog[t0 + tt][e], lacc[tt][e]);
  __syncthreads();

  if (tid < 64) {
    float lg[8], we[8];
#pragma unroll
    for (int e = 0; e < 8; ++e) lg[e] = slog[tid][e] + b2[e];
    float mx = lg[0];
#pragma unroll
    for (int e = 1; e < 8; ++e) mx = fmaxf(mx, lg[e]);
    float ssum = 0.f;
#pragma unroll
    for (int e = 0; e < 8; ++e) { we[e] = expf(lg[e] - mx); ssum += we[e]; }
#pragma unroll
    for (int e = 0; e < 8; ++e) we[e] = we[e] / ssum;
    float ent = 0.f;
#pragma unroll
    for (int e = 0; e < 8; ++e) ent += we[e] * logf(we[e] + 1e-8f);
    // top-2 of locals (ties -> lower index, matching lax.top_k)
    int i1 = 0; float v1 = we[2];
#pragma unroll
    for (int n = 1; n < 6; ++n) if (we[2 + n] > v1) { v1 = we[2 + n]; i1 = n; }
    int i2 = -1; float v2 = -1e30f;
#pragma unroll
    for (int n = 0; n < 6; ++n) if (n != i1 && we[2 + n] > v2) { v2 = we[2 + n]; i2 = n; }
    float ow[8];
    ow[0] = we[0]; ow[1] = we[1];
#pragma unroll
    for (int n = 0; n < 6; ++n) ow[2 + n] = 0.f;
    ow[2 + i1] = v1; ow[2 + i2] = v2;
    float* wp = wtok + (size_t)(tblk + tid) * 8;
#pragma unroll
    for (int e = 0; e < 8; ++e) wp[e] = ow[e];
    // wave-reduce entropy partial, one atomic per block
#pragma unroll
    for (int off = 32; off > 0; off >>= 1) ent += __shfl_down(ent, off);
    if (tid == 0) atomicAdd(entp, ent);
  }
}

// ---------------------------------------------------------------------------
// bf16 MFMA GEMM, m97 structure: 128x128 tile, BK=32, 4 waves (2x2 of 64x64),
// 16x16x32 MFMA, global_load_lds width 16, 2 barriers per K-step.
// A [M,K] bf16 row-major, Bt [N,K] bf16 (pre-transposed weights).
// MODE 0: C=bf16 gelu(acc+bias); MODE 1: pred(f32) (=/+=) wtok[:,eidx]*(acc+bias);
// MODE 2: C=f32 acc+bias.
// ---------------------------------------------------------------------------
template<int MODE, bool STORE>
__global__ __launch_bounds__(256)
void gemm_bf16_k(const __hip_bfloat16* __restrict__ A,
                 const __hip_bfloat16* __restrict__ Bt,
                 const float* __restrict__ bias,
                 void* __restrict__ Cout,
                 const float* __restrict__ wtok,
                 int M, int N, int K, int eidx)
{
  __shared__ __align__(16) unsigned short As[4096];  // [128][32] bf16
  __shared__ __align__(16) unsigned short Bs[4096];  // [128][32] bf16 (rows = out cols)
  const int tid  = threadIdx.x;
  const int wid  = tid >> 6;
  const int lane = tid & 63;
  const int wm = wid >> 1, wn = wid & 1;
  const int l15 = lane & 15, l4 = lane >> 4;

  v_f32x4 acc[4][4] = {};

  const size_t Kb = (size_t)K * 2;
  const char* Ag = (const char*)A + (size_t)blockIdx.x * 128 * Kb;
  const char* Bg = (const char*)Bt + (size_t)blockIdx.y * 128 * Kb;

  // staging geometry: 8KB per tile = 4 waves x 2 chunks x 64 lanes x 16B
  const int ob0 = (0 * 4 + wid) * 1024 + lane * 16;
  const int ob1 = (1 * 4 + wid) * 1024 + lane * 16;
  const int r0 = ob0 >> 6, kb0 = ob0 & 63;
  const int r1 = ob1 >> 6, kb1 = ob1 & 63;
  char* lA0 = (char*)As + (0 * 4 + wid) * 1024;
  char* lA1 = (char*)As + (1 * 4 + wid) * 1024;
  char* lB0 = (char*)Bs + (0 * 4 + wid) * 1024;
  char* lB1 = (char*)Bs + (1 * 4 + wid) * 1024;
  const char* gA0 = Ag + (size_t)r0 * Kb + kb0;
  const char* gA1 = Ag + (size_t)r1 * Kb + kb1;
  const char* gB0 = Bg + (size_t)r0 * Kb + kb0;
  const char* gB1 = Bg + (size_t)r1 * Kb + kb1;

  for (int kt = 0; kt < K; kt += 32) {
    size_t koff = (size_t)kt * 2;
    gload_lds16(gA0 + koff, lA0);
    gload_lds16(gA1 + koff, lA1);
    gload_lds16(gB0 + koff, lB0);
    gload_lds16(gB1 + koff, lB1);
    __syncthreads();   // vmcnt drain + barrier
    v_s16x8 af[4], bfv[4];
#pragma unroll
    for (int m = 0; m < 4; ++m)
      af[m] = *(const v_s16x8*)(As + (wm * 64 + m * 16 + l15) * 32 + l4 * 8);
#pragma unroll
    for (int n = 0; n < 4; ++n)
      bfv[n] = *(const v_s16x8*)(Bs + (wn * 64 + n * 16 + l15) * 32 + l4 * 8);
#pragma unroll
    for (int m = 0; m < 4; ++m)
#pragma unroll
      for (int n = 0; n < 4; ++n)
        acc[m][n] = __builtin_amdgcn_mfma_f32_16x16x32_bf16(af[m], bfv[n], acc[m][n], 0, 0, 0);
    __syncthreads();   // protect LDS before next stage
  }

  const int crow0 = blockIdx.x * 128 + wm * 64;
  const int ccol0 = blockIdx.y * 128 + wn * 64;
#pragma unroll
  for (int m = 0; m < 4; ++m) {
    float wv[4];
    if (MODE == 1) {
#pragma unroll
      for (int j = 0; j < 4; ++j)
        wv[j] = wtok[(size_t)(crow0 + m * 16 + l4 * 4 + j) * 8 + eidx];
    }
#pragma unroll
    for (int n = 0; n < 4; ++n) {
      const int col = ccol0 + n * 16 + l15;
      const float bv = bias[col];
#pragma unroll
      for (int j = 0; j < 4; ++j) {
        const int row = crow0 + m * 16 + l4 * 4 + j;
        float v = acc[m][n][j] + bv;
        if (MODE == 0) {
          ((__hip_bfloat16*)Cout)[(size_t)row * N + col] = __float2bfloat16(gelu_f(v));
        } else if (MODE == 1) {
          float* Pp = (float*)Cout + (size_t)row * N + col;
          float val = v * wv[j];
          if (STORE) *Pp = val; else *Pp += val;
        } else {
          ((float*)Cout)[(size_t)row * N + col] = v;
        }
      }
    }
  }
}

// ---------------------------------------------------------------------------
// small helper kernels
// ---------------------------------------------------------------------------
__global__ void zero_kernel(float* p) { p[0] = 0.f; }

__global__ void convert_x_kernel(const float* __restrict__ x,
                                 __hip_bfloat16* __restrict__ xb, int n4) {
  int stride = gridDim.x * blockDim.x;
  for (int i = blockIdx.x * blockDim.x + threadIdx.x; i < n4; i += stride) {
    float4 v = ((const float4*)x)[i];
    union { __hip_bfloat16 h[4]; ushort4 u; } cv;
    cv.h[0] = __float2bfloat16(v.x); cv.h[1] = __float2bfloat16(v.y);
    cv.h[2] = __float2bfloat16(v.z); cv.h[3] = __float2bfloat16(v.w);
    ((ushort4*)xb)[i] = cv.u;
  }
}

struct ConvDesc { const float* src; __hip_bfloat16* dst; int K; int N; };
struct ConvArgs { ConvDesc d[20]; };

// dst[n*K+k] = bf16(src[k*N+n]) : weight transpose+convert ([K,N] -> [N,K])
__global__ void convert_wt_kernel(ConvArgs a) {
  ConvDesc c = a.d[blockIdx.y];
  int total = c.K * c.N;
  int stride = gridDim.x * blockDim.x;
  for (int e = blockIdx.x * blockDim.x + threadIdx.x; e < total; e += stride) {
    int n = e / c.K;
    int k = e - n * c.K;
    c.dst[e] = __float2bfloat16(c.src[(size_t)k * c.N + n]);
  }
}

// meanz[r][o] = mean_c pred[r*512+c][o], r = s*32+b
__global__ void mean_kernel(const float* __restrict__ pred, float* __restrict__ meanz) {
  int r = blockIdx.x, o = threadIdx.x;
  const float* p = pred + (size_t)r * 512 * 256 + o;
  float s0 = 0.f, s1 = 0.f, s2 = 0.f, s3 = 0.f;
  for (int c = 0; c < 512; c += 4) {
    s0 += p[(size_t)(c + 0) * 256]; s1 += p[(size_t)(c + 1) * 256];
    s2 += p[(size_t)(c + 2) * 256]; s3 += p[(size_t)(c + 3) * 256];
  }
  meanz[r * 256 + o] = (s0 + s1 + s2 + s3) * (1.0f / 512.0f);
}

// reprs[r][j] = gelu(meanz[r]@te_w[:,j] + te_b[j])
__global__ void te_kernel(const float* __restrict__ meanz, const float* __restrict__ tw,
                          const float* __restrict__ tb, float* __restrict__ reprs) {
  __shared__ float row[256];
  int r = blockIdx.x, j = threadIdx.x;
  row[j] = meanz[r * 256 + j];
  __syncthreads();
  float a = 0.f;
  for (int k = 0; k < 256; ++k) a += row[k] * tw[k * 256 + j];
  reprs[r * 256 + j] = gelu_f(a + tb[j]);
}

// sw[b][:] = softmax(softplus(tanh(concat(reprs,mem)[b] @ wc_w + wc_b)))
__global__ void wc_kernel(const float* __restrict__ reprs, const float* __restrict__ wmem,
                          const float* __restrict__ wcw, const float* __restrict__ wcb,
                          float* __restrict__ sw) {
  __shared__ float red[128][3];
  int b = blockIdx.x, tid = threadIdx.x;
  float a0 = 0.f, a1 = 0.f, a2 = 0.f;
  for (int i = tid; i < 771; i += 128) {
    float cv = (i < 768) ? reprs[(i >> 8) * 8192 + b * 256 + (i & 255)] : wmem[i - 768];
    a0 += cv * wcw[i * 3 + 0]; a1 += cv * wcw[i * 3 + 1]; a2 += cv * wcw[i * 3 + 2];
  }
  red[tid][0] = a0; red[tid][1] = a1; red[tid][2] = a2;
  __syncthreads();
  for (int s = 64; s > 0; s >>= 1) {
    if (tid < s) {
      red[tid][0] += red[tid + s][0];
      red[tid][1] += red[tid + s][1];
      red[tid][2] += red[tid + s][2];
    }
    __syncthreads();
  }
  if (tid == 0) {
    float r[3]; float mx = -1e30f;
    for (int j = 0; j < 3; ++j) {
      float v = tanhf(red[0][j] + wcb[j]);
      r[j] = log1pf(expf(v));         // softplus, v in [-1,1]
      mx = fmaxf(mx, r[j]);
    }
    float s = 0.f;
    for (int j = 0; j < 3; ++j) { r[j] = expf(r[j] - mx); s += r[j]; }
    for (int j = 0; j < 3; ++j) sw[b * 3 + j] = r[j] / s;
  }
}

// wb[t][o] = bf16( sum_s pred[s][t][o] * sw[b][s] ), t = b*512+c
__global__ void weighted_kernel(const float* __restrict__ pred, const float* __restrict__ sw,
                                __hip_bfloat16* __restrict__ wb) {
  int t = blockIdx.x, o = threadIdx.x;
  int b = t >> 9;
  float s0 = sw[b * 3 + 0], s1 = sw[b * 3 + 1], s2 = sw[b * 3 + 2];
  size_t i = (size_t)t * 256 + o;
  float v = pred[i] * s0 + pred[i + (size_t)TBC_ * 256] * s1 + pred[i + (size_t)2 * TBC_ * 256] * s2;
  wb[i] = __float2bfloat16(v);
}

__global__ void finalize_kernel(const float* __restrict__ entp, float* __restrict__ out) {
  out[4194304] = -0.1f * entp[0] / 49152.0f;   // balance_loss = 0.1 * entropy
}

// ---------------------------------------------------------------------------
extern "C" void kernel_launch(void* const* d_in, const int* in_sizes, int n_in,
                              void* d_out, int out_size, void* d_ws, size_t ws_size,
                              hipStream_t stream) {
  const float* x    = (const float*)d_in[0];
  const float* rw1  = (const float*)d_in[1];
  const float* rb1  = (const float*)d_in[2];
  const float* rw2  = (const float*)d_in[3];
  const float* rb2  = (const float*)d_in[4];
  const float* gW1  = (const float*)d_in[5];
  const float* gb1  = (const float*)d_in[6];
  const float* gW2  = (const float*)d_in[7];
  const float* gb2  = (const float*)d_in[8];
  const float* gW3  = (const float*)d_in[9];
  const float* gb3  = (const float*)d_in[10];
  const float* lW1  = (const float*)d_in[11];
  const float* lb1  = (const float*)d_in[12];
  const float* lW2  = (const float*)d_in[13];
  const float* lb2  = (const float*)d_in[14];
  const float* tew  = (const float*)d_in[15];
  const float* teb  = (const float*)d_in[16];
  const float* wmem = (const float*)d_in[17];
  const float* wcw  = (const float*)d_in[18];
  const float* wcb  = (const float*)d_in[19];
  const float* ow1  = (const float*)d_in[20];
  const float* ob1  = (const float*)d_in[21];
  const float* ow2  = (const float*)d_in[22];
  const float* ob2  = (const float*)d_in[23];
  float* out = (float*)d_out;

  // workspace layout (~186 MB assumed available)
  char* ws = (char*)d_ws;
  size_t off = 0;
  auto alloc = [&](size_t bytes) -> void* {
    void* p = ws + off;
    off = (off + bytes + 255) & ~(size_t)255;
    return p;
  };
  __hip_bfloat16* Xb   = (__hip_bfloat16*)alloc((size_t)T_ * E_ * 2);
  __hip_bfloat16* gW1t = (__hip_bfloat16*)alloc(2ull * H_ * E_ * 2);
  __hip_bfloat16* gW2t = (__hip_bfloat16*)alloc(2ull * H_ * H_ * 2);
  __hip_bfloat16* gW3t = (__hip_bfloat16*)alloc(2ull * P_ * H_ * 2);
  __hip_bfloat16* lW1t = (__hip_bfloat16*)alloc(6ull * H_ * E_ * 2);
  __hip_bfloat16* lW2t = (__hip_bfloat16*)alloc(6ull * P_ * H_ * 2);
  __hip_bfloat16* ow1t = (__hip_bfloat16*)alloc((size_t)P_ * E_ * 2);
  __hip_bfloat16* ow2t = (__hip_bfloat16*)alloc((size_t)P_ * P_ * 2);
  float* wtok  = (float*)alloc((size_t)T_ * 8 * 4);
  float* entp  = (float*)alloc(256);
  float* meanz = (float*)alloc(96ull * 256 * 4);
  float* reprs = (float*)alloc(96ull * 256 * 4);
  float* swp   = (float*)alloc(512);
  __hip_bfloat16* bufA = (__hip_bfloat16*)alloc((size_t)T_ * H_ * 2);
  __hip_bfloat16* bufB = (__hip_bfloat16*)alloc((size_t)T_ * H_ * 2);
  float* pred = (float*)alloc((size_t)T_ * P_ * 4);
  __hip_bfloat16* wghtB = bufA;   // alias (bufA free after last local expert)
  __hip_bfloat16* out1B = bufB;   // alias

  // conversion descriptors (weights -> [N,K] bf16)
  ConvArgs ca;
  int d = 0;
  for (int s = 0; s < 2; ++s) ca.d[d++] = { gW1 + (size_t)s * E_ * H_, gW1t + (size_t)s * H_ * E_, E_, H_ };
  for (int s = 0; s < 2; ++s) ca.d[d++] = { gW2 + (size_t)s * H_ * H_, gW2t + (size_t)s * H_ * H_, H_, H_ };
  for (int s = 0; s < 2; ++s) ca.d[d++] = { gW3 + (size_t)s * H_ * P_, gW3t + (size_t)s * P_ * H_, H_, P_ };
  for (int n = 0; n < 6; ++n) ca.d[d++] = { lW1 + (size_t)n * E_ * H_, lW1t + (size_t)n * H_ * E_, E_, H_ };
  for (int n = 0; n < 6; ++n) ca.d[d++] = { lW2 + (size_t)n * H_ * P_, lW2t + (size_t)n * P_ * H_, H_, P_ };
  ca.d[d++] = { ow1, ow1t, E_, P_ };
  ca.d[d++] = { ow2, ow2t, P_, P_ };

  zero_kernel<<<1, 1, 0, stream>>>(entp);
  convert_x_kernel<<<1024, 256, 0, stream>>>(x, Xb, T_ * E_ / 4);
  convert_wt_kernel<<<dim3(64, 20), 256, 0, stream>>>(ca);
  router_kernel<<<T_ / 64, 256, 0, stream>>>(x, rw1, rb1, rw2, rb2, wtok, entp);

  // global (shared) experts: 3-layer chain, weighted accumulate into pred
  for (int s = 0; s < 2; ++s) {
    gemm_bf16_k<0, true><<<dim3(T_ / 128, H_ / 128), 256, 0, stream>>>(
        Xb, gW1t + (size_t)s * H_ * E_, gb1 + s * H_, bufA, nullptr, T_, H_, E_, 0);
    gemm_bf16_k<0, true><<<dim3(T_ / 128, H_ / 128), 256, 0, stream>>>(
        bufA, gW2t + (size_t)s * H_ * H_, gb2 + s * H_, bufB, nullptr, T_, H_, H_, 0);
    if (s == 0)
      gemm_bf16_k<1, true><<<dim3(T_ / 128, P_ / 128), 256, 0, stream>>>(
          bufB, gW3t + (size_t)s * P_ * H_, gb3 + s * P_, pred, wtok, T_, P_, H_, s);
    else
      gemm_bf16_k<1, false><<<dim3(T_ / 128, P_ / 128), 256, 0, stream>>>(
          bufB, gW3t + (size_t)s * P_ * H_, gb3 + s * P_, pred, wtok, T_, P_, H_, s);
  }
  // local experts: 2-layer chain, masked top-2 weights
  for (int n = 0; n < 6; ++n) {
    gemm_bf16_k<0, true><<<dim3(T_ / 128, H_ / 128), 256, 0, stream>>>(
        Xb, lW1t + (size_t)n * H_ * E_, lb1 + n * H_, bufA, nullptr, T_, H_, E_, 0);
    gemm_bf16_k<1, false><<<dim3(T_ / 128, P_ / 128), 256, 0, stream>>>(
        bufA, lW2t + (size_t)n * P_ * H_, lb2 + n * P_, pred, wtok, T_, P_, H_, 2 + n);
  }

  mean_kernel<<<96, 256, 0, stream>>>(pred, meanz);
  te_kernel<<<96, 256, 0, stream>>>(meanz, tew, teb, reprs);
  wc_kernel<<<32, 128, 0, stream>>>(reprs, wmem, wcw, wcb, swp);
  weighted_kernel<<<TBC_, 256, 0, stream>>>(pred, swp, wghtB);

  gemm_bf16_k<0, true><<<dim3(TBC_ / 128, P_ / 128), 256, 0, stream>>>(
      wghtB, ow1t, ob1, out1B, nullptr, TBC_, P_, E_, 0);
  gemm_bf16_k<2, true><<<dim3(TBC_ / 128, P_ / 128), 256, 0, stream>>>(
      out1B, ow2t, ob2, out, nullptr, TBC_, P_, P_, 0);

  finalize_kernel<<<1, 1, 0, stream>>>(entp, out);
  (void)in_sizes; (void)n_in; (void)out_size; (void)ws_size;
}

// Round 3
// 1021.836 us; speedup vs baseline: 1.3232x; 1.3232x over previous
//
#include <hip/hip_runtime.h>
#include <hip/hip_bf16.h>
#include <math.h>

// Problem constants (from reference)
#define S_   3
#define B_   32
#define C_   512
#define E_   256      // INPUT_DIM
#define H_   512      // HIDDEN_DIM
#define P_   256      // PRED_LEN
#define T_   49152    // S*B*C tokens (expert weights shared across scales -> flatten)
#define TBC_ 16384    // B*C

typedef __attribute__((ext_vector_type(8))) short v_s16x8;  // 8 bf16 (4 VGPR)
typedef __attribute__((ext_vector_type(4))) float v_f32x4;  // MFMA accumulator

__device__ __forceinline__ float gelu_f(float x) {
  // exact gelu (approximate=False): 0.5*x*(1+erf(x/sqrt(2)))
  return 0.5f * x * (1.0f + erff(x * 0.70710678118654752440f));
}

__device__ __forceinline__ void gload_lds16(const void* g, void* l) {
  // async global->LDS, 16B per lane; LDS dest = wave-uniform base + lane*16
  __builtin_amdgcn_global_load_lds((const __attribute__((address_space(1))) void*)g,
                                   (__attribute__((address_space(3))) void*)l, 16, 0, 0);
}

// ---------------------------------------------------------------------------
// bf16 MFMA GEMM, m97 structure: 128x128 tile, BK=32, 4 waves (2x2 of 64x64),
// 16x16x32 MFMA, global_load_lds width 16, 2 barriers per K-step.
// A [M,K] bf16 row-major, Bt [N,K] bf16 (pre-transposed weights).
// SPLITA: A has 256 real cols; virtual K=768 = [A_hi | A_lo | A_hi]
//         (split-bf16 fp32-emulation: acc = hi*hi + lo*hi + hi*lo).
// MODE 0: C=bf16 gelu(acc+bias); MODE 1: pred(f32) (=/+=) wtok[:,eidx]*(acc+bias);
// MODE 2: C=f32 acc+bias; MODE 3: C=f32 gelu(acc+bias).
// ---------------------------------------------------------------------------
template<int MODE, bool STORE, bool SPLITA>
__global__ __launch_bounds__(256)
void gemm_bf16_k(const __hip_bfloat16* __restrict__ A,
                 const __hip_bfloat16* __restrict__ Bt,
                 const float* __restrict__ bias,
                 void* __restrict__ Cout,
                 const float* __restrict__ wtok,
                 int M, int N, int K, int eidx,
                 const __hip_bfloat16* __restrict__ Alo)
{
  __shared__ __align__(16) unsigned short As[4096];  // [128][32] bf16
  __shared__ __align__(16) unsigned short Bs[4096];  // [128][32] bf16 (rows = out cols)
  const int tid  = threadIdx.x;
  const int wid  = tid >> 6;
  const int lane = tid & 63;
  const int wm = wid >> 1, wn = wid & 1;
  const int l15 = lane & 15, l4 = lane >> 4;

  v_f32x4 acc[4][4] = {};

  const size_t Kb   = (size_t)K * 2;            // Bt row stride (bytes)
  const size_t ArsB = SPLITA ? 512 : Kb;        // A row stride (bytes)
  const char* AgHi = (const char*)A + (size_t)blockIdx.x * 128 * ArsB;
  const char* AgLo = SPLITA ? ((const char*)Alo + (size_t)blockIdx.x * 128 * ArsB) : nullptr;
  const char* Bg   = (const char*)Bt + (size_t)blockIdx.y * 128 * Kb;

  // staging geometry: 8KB per tile = 4 waves x 2 chunks x 64 lanes x 16B
  const int ob0 = (0 * 4 + wid) * 1024 + lane * 16;
  const int ob1 = (1 * 4 + wid) * 1024 + lane * 16;
  const int r0 = ob0 >> 6, kb0 = ob0 & 63;
  const int r1 = ob1 >> 6, kb1 = ob1 & 63;
  char* lA0 = (char*)As + (0 * 4 + wid) * 1024;
  char* lA1 = (char*)As + (1 * 4 + wid) * 1024;
  char* lB0 = (char*)Bs + (0 * 4 + wid) * 1024;
  char* lB1 = (char*)Bs + (1 * 4 + wid) * 1024;
  const size_t aoff0 = (size_t)r0 * ArsB + kb0;
  const size_t aoff1 = (size_t)r1 * ArsB + kb1;
  const char* gB0 = Bg + (size_t)r0 * Kb + kb0;
  const char* gB1 = Bg + (size_t)r1 * Kb + kb1;

  for (int kt = 0; kt < K; kt += 32) {
    const char* Asrc = AgHi;
    size_t akt = (size_t)kt * 2;
    if (SPLITA) {
      akt = (size_t)(kt & 255) * 2;
      if ((kt >> 8) == 1) Asrc = AgLo;
    }
    size_t bkt = (size_t)kt * 2;
    gload_lds16(Asrc + aoff0 + akt, lA0);
    gload_lds16(Asrc + aoff1 + akt, lA1);
    gload_lds16(gB0 + bkt, lB0);
    gload_lds16(gB1 + bkt, lB1);
    __syncthreads();   // vmcnt drain + barrier
    v_s16x8 af[4], bfv[4];
#pragma unroll
    for (int m = 0; m < 4; ++m)
      af[m] = *(const v_s16x8*)(As + (wm * 64 + m * 16 + l15) * 32 + l4 * 8);
#pragma unroll
    for (int n = 0; n < 4; ++n)
      bfv[n] = *(const v_s16x8*)(Bs + (wn * 64 + n * 16 + l15) * 32 + l4 * 8);
#pragma unroll
    for (int m = 0; m < 4; ++m)
#pragma unroll
      for (int n = 0; n < 4; ++n)
        acc[m][n] = __builtin_amdgcn_mfma_f32_16x16x32_bf16(af[m], bfv[n], acc[m][n], 0, 0, 0);
    __syncthreads();   // protect LDS before next stage
  }

  const int crow0 = blockIdx.x * 128 + wm * 64;
  const int ccol0 = blockIdx.y * 128 + wn * 64;
#pragma unroll
  for (int m = 0; m < 4; ++m) {
    float wv[4];
    if (MODE == 1) {
#pragma unroll
      for (int j = 0; j < 4; ++j)
        wv[j] = wtok[(size_t)(crow0 + m * 16 + l4 * 4 + j) * 8 + eidx];
    }
#pragma unroll
    for (int n = 0; n < 4; ++n) {
      const int col = ccol0 + n * 16 + l15;
      const float bv = bias[col];
#pragma unroll
      for (int j = 0; j < 4; ++j) {
        const int row = crow0 + m * 16 + l4 * 4 + j;
        float v = acc[m][n][j] + bv;
        if (MODE == 0) {
          ((__hip_bfloat16*)Cout)[(size_t)row * N + col] = __float2bfloat16(gelu_f(v));
        } else if (MODE == 1) {
          float* Pp = (float*)Cout + (size_t)row * N + col;
          float val = v * wv[j];
          if (STORE) *Pp = val; else *Pp += val;
        } else if (MODE == 2) {
          ((float*)Cout)[(size_t)row * N + col] = v;
        } else {
          ((float*)Cout)[(size_t)row * N + col] = gelu_f(v);
        }
      }
    }
  }
}

// ---------------------------------------------------------------------------
// logits/softmax/top-2/entropy: one token per thread, no LDS for data.
// hr rows read as sequential float4 per lane (L1-friendly); w2/b2 are
// block-uniform -> scalar loads.
// ---------------------------------------------------------------------------
__global__ __launch_bounds__(256) void logits_kernel(
    const float* __restrict__ hr,   // [T,512] fp32 gelu'd hidden
    const float* __restrict__ w2,   // [512,8]
    const float* __restrict__ b2,   // [8]
    float* __restrict__ wtok,       // [T,8]
    float* __restrict__ entp)       // [1]
{
  const int t = blockIdx.x * 256 + threadIdx.x;
  const float4* hrow = (const float4*)(hr + (size_t)t * 512);
  float lg[8];
#pragma unroll
  for (int e = 0; e < 8; ++e) lg[e] = b2[e];
#pragma unroll 4
  for (int k4 = 0; k4 < 128; ++k4) {
    float4 hv = hrow[k4];
    float hvv[4] = {hv.x, hv.y, hv.z, hv.w};
#pragma unroll
    for (int j = 0; j < 4; ++j) {
      const float* wr = w2 + (k4 * 4 + j) * 8;
#pragma unroll
      for (int e = 0; e < 8; ++e) lg[e] += hvv[j] * wr[e];
    }
  }
  float we[8];
  float mx = lg[0];
#pragma unroll
  for (int e = 1; e < 8; ++e) mx = fmaxf(mx, lg[e]);
  float ssum = 0.f;
#pragma unroll
  for (int e = 0; e < 8; ++e) { we[e] = expf(lg[e] - mx); ssum += we[e]; }
#pragma unroll
  for (int e = 0; e < 8; ++e) we[e] = we[e] / ssum;
  float ent = 0.f;
#pragma unroll
  for (int e = 0; e < 8; ++e) ent += we[e] * logf(we[e] + 1e-8f);
  // top-2 of locals (ties -> lower index, matching lax.top_k)
  int i1 = 0; float v1 = we[2];
#pragma unroll
  for (int n = 1; n < 6; ++n) if (we[2 + n] > v1) { v1 = we[2 + n]; i1 = n; }
  int i2 = -1; float v2 = -1e30f;
#pragma unroll
  for (int n = 0; n < 6; ++n) if (n != i1 && we[2 + n] > v2) { v2 = we[2 + n]; i2 = n; }
  float ow[8];
  ow[0] = we[0]; ow[1] = we[1];
#pragma unroll
  for (int n = 0; n < 6; ++n) ow[2 + n] = 0.f;
  ow[2 + i1] = v1; ow[2 + i2] = v2;
  float* wp = wtok + (size_t)t * 8;
#pragma unroll
  for (int e = 0; e < 8; ++e) wp[e] = ow[e];
  // block-reduce entropy, one atomic per block
  __shared__ float red[256];
  red[threadIdx.x] = ent;
  __syncthreads();
  for (int s = 128; s > 0; s >>= 1) {
    if (threadIdx.x < s) red[threadIdx.x] += red[threadIdx.x + s];
    __syncthreads();
  }
  if (threadIdx.x == 0) atomicAdd(entp, red[0]);
}

// ---------------------------------------------------------------------------
// small helper kernels
// ---------------------------------------------------------------------------
__global__ void zero_kernel(float* p) { p[0] = 0.f; }

// x -> bf16 hi + bf16 lo (split for fp32-emulated router GEMM)
__global__ void convert_x_kernel(const float* __restrict__ x,
                                 __hip_bfloat16* __restrict__ xb,
                                 __hip_bfloat16* __restrict__ xlo, int n4) {
  int stride = gridDim.x * blockDim.x;
  for (int i = blockIdx.x * blockDim.x + threadIdx.x; i < n4; i += stride) {
    float4 v = ((const float4*)x)[i];
    float vv[4] = {v.x, v.y, v.z, v.w};
    union { __hip_bfloat16 h[4]; ushort4 u; } hi, lo;
#pragma unroll
    for (int j = 0; j < 4; ++j) {
      hi.h[j] = __float2bfloat16(vv[j]);
      lo.h[j] = __float2bfloat16(vv[j] - __bfloat162float(hi.h[j]));
    }
    ((ushort4*)xb)[i] = hi.u;
    ((ushort4*)xlo)[i] = lo.u;
  }
}

// router W1 -> [N=512][K=768] bf16: cols 0..255 = W_hi, 256..511 = W_hi, 512..767 = W_lo
__global__ void build_router_w_kernel(const float* __restrict__ rw1,
                                      __hip_bfloat16* __restrict__ dst) {
  int i = blockIdx.x * 256 + threadIdx.x;   // 512*768 total
  int n = i / 768, k = i - n * 768;
  float src = rw1[(size_t)(k & 255) * 512 + n];
  __hip_bfloat16 hv = __float2bfloat16(src);
  dst[i] = (k < 512) ? hv : __float2bfloat16(src - __bfloat162float(hv));
}

struct ConvDesc { const float* src; __hip_bfloat16* dst; int K; int N; };
struct ConvArgs { ConvDesc d[20]; };

// dst[n*K+k] = bf16(src[k*N+n]) : weight transpose+convert ([K,N] -> [N,K])
__global__ void convert_wt_kernel(ConvArgs a) {
  ConvDesc c = a.d[blockIdx.y];
  int total = c.K * c.N;
  int stride = gridDim.x * blockDim.x;
  for (int e = blockIdx.x * blockDim.x + threadIdx.x; e < total; e += stride) {
    int n = e / c.K;
    int k = e - n * c.K;
    c.dst[e] = __float2bfloat16(c.src[(size_t)k * c.N + n]);
  }
}

// meanz[r][o] = mean_c pred[r*512+c][o], r = s*32+b
__global__ void mean_kernel(const float* __restrict__ pred, float* __restrict__ meanz) {
  int r = blockIdx.x, o = threadIdx.x;
  const float* p = pred + (size_t)r * 512 * 256 + o;
  float s0 = 0.f, s1 = 0.f, s2 = 0.f, s3 = 0.f;
  for (int c = 0; c < 512; c += 4) {
    s0 += p[(size_t)(c + 0) * 256]; s1 += p[(size_t)(c + 1) * 256];
    s2 += p[(size_t)(c + 2) * 256]; s3 += p[(size_t)(c + 3) * 256];
  }
  meanz[r * 256 + o] = (s0 + s1 + s2 + s3) * (1.0f / 512.0f);
}

// reprs[r][j] = gelu(meanz[r]@te_w[:,j] + te_b[j])
__global__ void te_kernel(const float* __restrict__ meanz, const float* __restrict__ tw,
                          const float* __restrict__ tb, float* __restrict__ reprs) {
  __shared__ float row[256];
  int r = blockIdx.x, j = threadIdx.x;
  row[j] = meanz[r * 256 + j];
  __syncthreads();
  float a = 0.f;
  for (int k = 0; k < 256; ++k) a += row[k] * tw[k * 256 + j];
  reprs[r * 256 + j] = gelu_f(a + tb[j]);
}

// sw[b][:] = softmax(softplus(tanh(concat(reprs,mem)[b] @ wc_w + wc_b)))
__global__ void wc_kernel(const float* __restrict__ reprs, const float* __restrict__ wmem,
                          const float* __restrict__ wcw, const float* __restrict__ wcb,
                          float* __restrict__ sw) {
  __shared__ float red[128][3];
  int b = blockIdx.x, tid = threadIdx.x;
  float a0 = 0.f, a1 = 0.f, a2 = 0.f;
  for (int i = tid; i < 771; i += 128) {
    float cv = (i < 768) ? reprs[(i >> 8) * 8192 + b * 256 + (i & 255)] : wmem[i - 768];
    a0 += cv * wcw[i * 3 + 0]; a1 += cv * wcw[i * 3 + 1]; a2 += cv * wcw[i * 3 + 2];
  }
  red[tid][0] = a0; red[tid][1] = a1; red[tid][2] = a2;
  __syncthreads();
  for (int s = 64; s > 0; s >>= 1) {
    if (tid < s) {
      red[tid][0] += red[tid + s][0];
      red[tid][1] += red[tid + s][1];
      red[tid][2] += red[tid + s][2];
    }
    __syncthreads();
  }
  if (tid == 0) {
    float r[3]; float mx = -1e30f;
    for (int j = 0; j < 3; ++j) {
      float v = tanhf(red[0][j] + wcb[j]);
      r[j] = log1pf(expf(v));         // softplus, v in [-1,1]
      mx = fmaxf(mx, r[j]);
    }
    float s = 0.f;
    for (int j = 0; j < 3; ++j) { r[j] = expf(r[j] - mx); s += r[j]; }
    for (int j = 0; j < 3; ++j) sw[b * 3 + j] = r[j] / s;
  }
}

// wb[t][o] = bf16( sum_s pred[s][t][o] * sw[b][s] ), t = b*512+c
__global__ void weighted_kernel(const float* __restrict__ pred, const float* __restrict__ sw,
                                __hip_bfloat16* __restrict__ wb) {
  int t = blockIdx.x, o = threadIdx.x;
  int b = t >> 9;
  float s0 = sw[b * 3 + 0], s1 = sw[b * 3 + 1], s2 = sw[b * 3 + 2];
  size_t i = (size_t)t * 256 + o;
  float v = pred[i] * s0 + pred[i + (size_t)TBC_ * 256] * s1 + pred[i + (size_t)2 * TBC_ * 256] * s2;
  wb[i] = __float2bfloat16(v);
}

__global__ void finalize_kernel(const float* __restrict__ entp, float* __restrict__ out) {
  out[4194304] = -0.1f * entp[0] / 49152.0f;   // balance_loss = 0.1 * entropy
}

// ---------------------------------------------------------------------------
extern "C" void kernel_launch(void* const* d_in, const int* in_sizes, int n_in,
                              void* d_out, int out_size, void* d_ws, size_t ws_size,
                              hipStream_t stream) {
  const float* x    = (const float*)d_in[0];
  const float* rw1  = (const float*)d_in[1];
  const float* rb1  = (const float*)d_in[2];
  const float* rw2  = (const float*)d_in[3];
  const float* rb2  = (const float*)d_in[4];
  const float* gW1  = (const float*)d_in[5];
  const float* gb1  = (const float*)d_in[6];
  const float* gW2  = (const float*)d_in[7];
  const float* gb2  = (const float*)d_in[8];
  const float* gW3  = (const float*)d_in[9];
  const float* gb3  = (const float*)d_in[10];
  const float* lW1  = (const float*)d_in[11];
  const float* lb1  = (const float*)d_in[12];
  const float* lW2  = (const float*)d_in[13];
  const float* lb2  = (const float*)d_in[14];
  const float* tew  = (const float*)d_in[15];
  const float* teb  = (const float*)d_in[16];
  const float* wmem = (const float*)d_in[17];
  const float* wcw  = (const float*)d_in[18];
  const float* wcb  = (const float*)d_in[19];
  const float* ow1  = (const float*)d_in[20];
  const float* ob1  = (const float*)d_in[21];
  const float* ow2  = (const float*)d_in[22];
  const float* ob2  = (const float*)d_in[23];
  float* out = (float*)d_out;

  // workspace layout (~206 MB)
  char* ws = (char*)d_ws;
  size_t off = 0;
  auto alloc = [&](size_t bytes) -> void* {
    void* p = ws + off;
    off = (off + bytes + 255) & ~(size_t)255;
    return p;
  };
  __hip_bfloat16* Xb   = (__hip_bfloat16*)alloc((size_t)T_ * E_ * 2);
  __hip_bfloat16* Xlo  = (__hip_bfloat16*)alloc((size_t)T_ * E_ * 2);
  __hip_bfloat16* rW1s = (__hip_bfloat16*)alloc(512ull * 768 * 2);
  __hip_bfloat16* gW1t = (__hip_bfloat16*)alloc(2ull * H_ * E_ * 2);
  __hip_bfloat16* gW2t = (__hip_bfloat16*)alloc(2ull * H_ * H_ * 2);
  __hip_bfloat16* gW3t = (__hip_bfloat16*)alloc(2ull * P_ * H_ * 2);
  __hip_bfloat16* lW1t = (__hip_bfloat16*)alloc(6ull * H_ * E_ * 2);
  __hip_bfloat16* lW2t = (__hip_bfloat16*)alloc(6ull * P_ * H_ * 2);
  __hip_bfloat16* ow1t = (__hip_bfloat16*)alloc((size_t)P_ * E_ * 2);
  __hip_bfloat16* ow2t = (__hip_bfloat16*)alloc((size_t)P_ * P_ * 2);
  float* wtok  = (float*)alloc((size_t)T_ * 8 * 4);
  float* entp  = (float*)alloc(256);
  float* meanz = (float*)alloc(96ull * 256 * 4);
  float* reprs = (float*)alloc(96ull * 256 * 4);
  float* swp   = (float*)alloc(512);
  __hip_bfloat16* bufA = (__hip_bfloat16*)alloc((size_t)T_ * H_ * 2);
  __hip_bfloat16* bufB = (__hip_bfloat16*)alloc((size_t)T_ * H_ * 2);
  float* pred = (float*)alloc((size_t)T_ * P_ * 4);
  // Hr (router hidden, fp32 [T,512] = 100.66 MB) aliases bufB+pred exactly:
  // written by router GEMM, consumed by logits_kernel, both dead before
  // the expert GEMMs first write bufB/pred.
  float* Hr = (float*)bufB;
  __hip_bfloat16* wghtB = bufA;   // alias (bufA free after last local expert)
  __hip_bfloat16* out1B = bufB;   // alias

  // conversion descriptors (weights -> [N,K] bf16)
  ConvArgs ca;
  int d = 0;
  for (int s = 0; s < 2; ++s) ca.d[d++] = { gW1 + (size_t)s * E_ * H_, gW1t + (size_t)s * H_ * E_, E_, H_ };
  for (int s = 0; s < 2; ++s) ca.d[d++] = { gW2 + (size_t)s * H_ * H_, gW2t + (size_t)s * H_ * H_, H_, H_ };
  for (int s = 0; s < 2; ++s) ca.d[d++] = { gW3 + (size_t)s * H_ * P_, gW3t + (size_t)s * P_ * H_, H_, P_ };
  for (int n = 0; n < 6; ++n) ca.d[d++] = { lW1 + (size_t)n * E_ * H_, lW1t + (size_t)n * H_ * E_, E_, H_ };
  for (int n = 0; n < 6; ++n) ca.d[d++] = { lW2 + (size_t)n * H_ * P_, lW2t + (size_t)n * P_ * H_, H_, P_ };
  ca.d[d++] = { ow1, ow1t, E_, P_ };
  ca.d[d++] = { ow2, ow2t, P_, P_ };

  zero_kernel<<<1, 1, 0, stream>>>(entp);
  convert_x_kernel<<<1024, 256, 0, stream>>>(x, Xb, Xlo, T_ * E_ / 4);
  convert_wt_kernel<<<dim3(64, 20), 256, 0, stream>>>(ca);
  build_router_w_kernel<<<1536, 256, 0, stream>>>(rw1, rW1s);

  // router layer-1 as split-bf16 GEMM (fp32-emulated): h = gelu(x@rw1+rb1), fp32 out
  gemm_bf16_k<3, true, true><<<dim3(T_ / 128, 512 / 128), 256, 0, stream>>>(
      Xb, rW1s, rb1, Hr, nullptr, T_, 512, 768, 0, Xlo);
  // logits + softmax + top-2 + entropy
  logits_kernel<<<T_ / 256, 256, 0, stream>>>(Hr, rw2, rb2, wtok, entp);

  // global (shared) experts: 3-layer chain, weighted accumulate into pred
  for (int s = 0; s < 2; ++s) {
    gemm_bf16_k<0, true, false><<<dim3(T_ / 128, H_ / 128), 256, 0, stream>>>(
        Xb, gW1t + (size_t)s * H_ * E_, gb1 + s * H_, bufA, nullptr, T_, H_, E_, 0, nullptr);
    gemm_bf16_k<0, true, false><<<dim3(T_ / 128, H_ / 128), 256, 0, stream>>>(
        bufA, gW2t + (size_t)s * H_ * H_, gb2 + s * H_, bufB, nullptr, T_, H_, H_, 0, nullptr);
    if (s == 0)
      gemm_bf16_k<1, true, false><<<dim3(T_ / 128, P_ / 128), 256, 0, stream>>>(
          bufB, gW3t + (size_t)s * P_ * H_, gb3 + s * P_, pred, wtok, T_, P_, H_, s, nullptr);
    else
      gemm_bf16_k<1, false, false><<<dim3(T_ / 128, P_ / 128), 256, 0, stream>>>(
          bufB, gW3t + (size_t)s * P_ * H_, gb3 + s * P_, pred, wtok, T_, P_, H_, s, nullptr);
  }
  // local experts: 2-layer chain, masked top-2 weights
  for (int n = 0; n < 6; ++n) {
    gemm_bf16_k<0, true, false><<<dim3(T_ / 128, H_ / 128), 256, 0, stream>>>(
        Xb, lW1t + (size_t)n * H_ * E_, lb1 + n * H_, bufA, nullptr, T_, H_, E_, 0, nullptr);
    gemm_bf16_k<1, false, false><<<dim3(T_ / 128, P_ / 128), 256, 0, stream>>>(
        bufA, lW2t + (size_t)n * P_ * H_, lb2 + n * P_, pred, wtok, T_, P_, H_, 2 + n, nullptr);
  }

  mean_kernel<<<96, 256, 0, stream>>>(pred, meanz);
  te_kernel<<<96, 256, 0, stream>>>(meanz, tew, teb, reprs);
  wc_kernel<<<32, 128, 0, stream>>>(reprs, wmem, wcw, wcb, swp);
  weighted_kernel<<<TBC_, 256, 0, stream>>>(pred, swp, wghtB);

  gemm_bf16_k<0, true, false><<<dim3(TBC_ / 128, P_ / 128), 256, 0, stream>>>(
      wghtB, ow1t, ob1, out1B, nullptr, TBC_, P_, E_, 0, nullptr);
  gemm_bf16_k<2, true, false><<<dim3(TBC_ / 128, P_ / 128), 256, 0, stream>>>(
      out1B, ow2t, ob2, out, nullptr, TBC_, P_, P_, 0, nullptr);

  finalize_kernel<<<1, 1, 0, stream>>>(entp, out);
  (void)in_sizes; (void)n_in; (void)out_size; (void)ws_size;
}

// Round 5
// 1017.090 us; speedup vs baseline: 1.3294x; 1.0047x over previous
//
#include <hip/hip_runtime.h>
#include <hip/hip_bf16.h>
#include <math.h>

// Problem constants (from reference)
#define S_   3
#define B_   32
#define C_   512
#define E_   256      // INPUT_DIM
#define H_   512      // HIDDEN_DIM
#define P_   256      // PRED_LEN
#define T_   49152    // S*B*C tokens (expert weights shared across scales -> flatten)
#define TBC_ 16384    // B*C

typedef __attribute__((ext_vector_type(8))) short v_s16x8;  // 8 bf16 (4 VGPR)
typedef __attribute__((ext_vector_type(4))) float v_f32x4;  // MFMA accumulator

__device__ __forceinline__ float gelu_f(float x) {
  // exact gelu (approximate=False): 0.5*x*(1+erf(x/sqrt(2)))
  return 0.5f * x * (1.0f + erff(x * 0.70710678118654752440f));
}

__device__ __forceinline__ void gload_lds16(const void* g, void* l) {
  // async global->LDS, 16B per lane; LDS dest = wave-uniform base + lane*16
  __builtin_amdgcn_global_load_lds((const __attribute__((address_space(1))) void*)g,
                                   (__attribute__((address_space(3))) void*)l, 16, 0, 0);
}

// ---------------------------------------------------------------------------
// bf16 MFMA GEMM, m97 structure: 128x128 tile, BK=32, 4 waves (2x2 of 64x64),
// 16x16x32 MFMA, global_load_lds width 16, 2 barriers per K-step.
// A [M,K] bf16 (row stride lda elems), Bt [N,K] bf16 (row stride ldb elems).
// SPLITA: A has 256 real cols; virtual K=768 = [A_hi | A_lo | A_hi].
// MODE 0: bf16 gelu(acc+bias)
// MODE 1: f32 (=/+=) wtok[row][eidx]*(acc+bias)            [serial fallback]
// MODE 2: f32 acc+bias
// MODE 3: f32 gelu(acc+bias)                               [router]
// MODE 4: bf16 wtok[row][eidxBase+(col>>9)]*gelu(acc+bias) [scaled hidden]
// MODE 6: f32 pred: STORE -> acc + sum_e wtok[row][e]*Ball[e][col]; else += acc
// MODE 7: col<1024 -> bf16 gelu to Gout[row*1024+col]; else as MODE 4 (base 0)
// ---------------------------------------------------------------------------
template<int MODE, bool STORE, bool SPLITA>
__global__ __launch_bounds__(256)
void gemm_bf16_k(const __hip_bfloat16* __restrict__ A,
                 const __hip_bfloat16* __restrict__ Bt,
                 const float* __restrict__ bias,
                 void* __restrict__ Cout,
                 const float* __restrict__ wtok,
                 int M, int N, int K, int eidxBase,
                 const __hip_bfloat16* __restrict__ Alo,
                 int lda, int ldb, int ldc,
                 __hip_bfloat16* __restrict__ Gout,
                 const float* __restrict__ Ball)
{
  __shared__ __align__(16) unsigned short As[4096];  // [128][32] bf16
  __shared__ __align__(16) unsigned short Bs[4096];  // [128][32] bf16 (rows = out cols)
  __shared__ float BallS[(MODE == 6 && STORE) ? 2048 : 1];
  const int tid  = threadIdx.x;
  const int wid  = tid >> 6;
  const int lane = tid & 63;
  const int wm = wid >> 1, wn = wid & 1;
  const int l15 = lane & 15, l4 = lane >> 4;

  if constexpr (MODE == 6 && STORE) {
    for (int i = tid; i < 2048; i += 256) BallS[i] = Ball[i];
    // first in-loop __syncthreads() makes these visible before epilogue use
  }

  v_f32x4 acc[4][4] = {};

  const size_t ArsB = (size_t)lda * 2;   // A row stride bytes
  const size_t BrsB = (size_t)ldb * 2;   // Bt row stride bytes
  const char* AgHi = (const char*)A + (size_t)blockIdx.x * 128 * ArsB;
  const char* AgLo = SPLITA ? ((const char*)Alo + (size_t)blockIdx.x * 128 * ArsB) : nullptr;
  const char* Bg   = (const char*)Bt + (size_t)blockIdx.y * 128 * BrsB;

  // staging geometry: 8KB per tile = 4 waves x 2 chunks x 64 lanes x 16B
  const int ob0 = (0 * 4 + wid) * 1024 + lane * 16;
  const int ob1 = (1 * 4 + wid) * 1024 + lane * 16;
  const int r0 = ob0 >> 6, kb0 = ob0 & 63;
  const int r1 = ob1 >> 6, kb1 = ob1 & 63;
  char* lA0 = (char*)As + (0 * 4 + wid) * 1024;
  char* lA1 = (char*)As + (1 * 4 + wid) * 1024;
  char* lB0 = (char*)Bs + (0 * 4 + wid) * 1024;
  char* lB1 = (char*)Bs + (1 * 4 + wid) * 1024;
  const size_t aoff0 = (size_t)r0 * ArsB + kb0;
  const size_t aoff1 = (size_t)r1 * ArsB + kb1;
  const char* gB0 = Bg + (size_t)r0 * BrsB + kb0;
  const char* gB1 = Bg + (size_t)r1 * BrsB + kb1;

  for (int kt = 0; kt < K; kt += 32) {
    const char* Asrc = AgHi;
    size_t akt = (size_t)kt * 2;
    if (SPLITA) {
      akt = (size_t)(kt & 255) * 2;
      if ((kt >> 8) == 1) Asrc = AgLo;
    }
    size_t bkt = (size_t)kt * 2;
    gload_lds16(Asrc + aoff0 + akt, lA0);
    gload_lds16(Asrc + aoff1 + akt, lA1);
    gload_lds16(gB0 + bkt, lB0);
    gload_lds16(gB1 + bkt, lB1);
    __syncthreads();   // vmcnt drain + barrier
    v_s16x8 af[4], bfv[4];
#pragma unroll
    for (int m = 0; m < 4; ++m)
      af[m] = *(const v_s16x8*)(As + (wm * 64 + m * 16 + l15) * 32 + l4 * 8);
#pragma unroll
    for (int n = 0; n < 4; ++n)
      bfv[n] = *(const v_s16x8*)(Bs + (wn * 64 + n * 16 + l15) * 32 + l4 * 8);
#pragma unroll
    for (int m = 0; m < 4; ++m)
#pragma unroll
      for (int n = 0; n < 4; ++n)
        acc[m][n] = __builtin_amdgcn_mfma_f32_16x16x32_bf16(af[m], bfv[n], acc[m][n], 0, 0, 0);
    __syncthreads();   // protect LDS before next stage
  }

  const int crow0 = blockIdx.x * 128 + wm * 64;
  const int ccol0 = blockIdx.y * 128 + wn * 64;

  if constexpr (MODE == 6) {
    // fused final accumulate: pred[row*ldc+col]
    float* P = (float*)Cout;
#pragma unroll
    for (int m = 0; m < 4; ++m) {
      float4 w0[4], w1[4];
      if (STORE) {
#pragma unroll
        for (int j = 0; j < 4; ++j) {
          const float4* wp = (const float4*)&wtok[(size_t)(crow0 + m * 16 + l4 * 4 + j) * 8];
          w0[j] = wp[0]; w1[j] = wp[1];
        }
      }
#pragma unroll
      for (int n = 0; n < 4; ++n) {
        const int col = ccol0 + n * 16 + l15;
        float bs[8];
        if (STORE) {
#pragma unroll
          for (int e = 0; e < 8; ++e) bs[e] = BallS[e * 256 + col];
        }
#pragma unroll
        for (int j = 0; j < 4; ++j) {
          const int row = crow0 + m * 16 + l4 * 4 + j;
          float v = acc[m][n][j];
          if (STORE) {
            v += bs[0] * w0[j].x + bs[1] * w0[j].y + bs[2] * w0[j].z + bs[3] * w0[j].w
               + bs[4] * w1[j].x + bs[5] * w1[j].y + bs[6] * w1[j].z + bs[7] * w1[j].w;
            P[(size_t)row * ldc + col] = v;
          } else {
            P[(size_t)row * ldc + col] += v;
          }
        }
      }
    }
    return;
  }

#pragma unroll
  for (int m = 0; m < 4; ++m) {
    float wv[4];
    if (MODE == 1 || MODE == 4 || MODE == 7) {
      int e4 = 0;
      if (MODE == 1) e4 = eidxBase;
      if (MODE == 4) e4 = eidxBase + (ccol0 >> 9);
      if (MODE == 7) e4 = (ccol0 >> 9);   // valid only when ccol0>=1024 (e=2,3)
#pragma unroll
      for (int j = 0; j < 4; ++j)
        wv[j] = wtok[(size_t)(crow0 + m * 16 + l4 * 4 + j) * 8 + e4];
    }
#pragma unroll
    for (int n = 0; n < 4; ++n) {
      const int col = ccol0 + n * 16 + l15;
      const float bv = bias[col];
#pragma unroll
      for (int j = 0; j < 4; ++j) {
        const int row = crow0 + m * 16 + l4 * 4 + j;
        float v = acc[m][n][j] + bv;
        if constexpr (MODE == 0) {
          ((__hip_bfloat16*)Cout)[(size_t)row * ldc + col] = __float2bfloat16(gelu_f(v));
        } else if constexpr (MODE == 1) {
          float* Pp = (float*)Cout + (size_t)row * ldc + col;
          float val = v * wv[j];
          if (STORE) *Pp = val; else *Pp += val;
        } else if constexpr (MODE == 2) {
          ((float*)Cout)[(size_t)row * ldc + col] = v;
        } else if constexpr (MODE == 3) {
          ((float*)Cout)[(size_t)row * ldc + col] = gelu_f(v);
        } else if constexpr (MODE == 4) {
          ((__hip_bfloat16*)Cout)[(size_t)row * ldc + col] = __float2bfloat16(wv[j] * gelu_f(v));
        } else if constexpr (MODE == 7) {
          if (ccol0 < 1024) {
            Gout[(size_t)row * 1024 + col] = __float2bfloat16(gelu_f(v));
          } else {
            ((__hip_bfloat16*)Cout)[(size_t)row * ldc + col] = __float2bfloat16(wv[j] * gelu_f(v));
          }
        }
      }
    }
  }
}

// ---------------------------------------------------------------------------
// logits/softmax/top-2/entropy: one token per thread.
// ---------------------------------------------------------------------------
__global__ __launch_bounds__(256) void logits_kernel(
    const float* __restrict__ hr,   // [T,512] fp32 gelu'd hidden
    const float* __restrict__ w2,   // [512,8]
    const float* __restrict__ b2,   // [8]
    float* __restrict__ wtok,       // [T,8]
    float* __restrict__ entp)       // [1]
{
  const int t = blockIdx.x * 256 + threadIdx.x;
  const float4* hrow = (const float4*)(hr + (size_t)t * 512);
  float lg[8];
#pragma unroll
  for (int e = 0; e < 8; ++e) lg[e] = b2[e];
#pragma unroll 4
  for (int k4 = 0; k4 < 128; ++k4) {
    float4 hv = hrow[k4];
    float hvv[4] = {hv.x, hv.y, hv.z, hv.w};
#pragma unroll
    for (int j = 0; j < 4; ++j) {
      const float* wr = w2 + (k4 * 4 + j) * 8;
#pragma unroll
      for (int e = 0; e < 8; ++e) lg[e] += hvv[j] * wr[e];
    }
  }
  float we[8];
  float mx = lg[0];
#pragma unroll
  for (int e = 1; e < 8; ++e) mx = fmaxf(mx, lg[e]);
  float ssum = 0.f;
#pragma unroll
  for (int e = 0; e < 8; ++e) { we[e] = expf(lg[e] - mx); ssum += we[e]; }
#pragma unroll
  for (int e = 0; e < 8; ++e) we[e] = we[e] / ssum;
  float ent = 0.f;
#pragma unroll
  for (int e = 0; e < 8; ++e) ent += we[e] * logf(we[e] + 1e-8f);
  // top-2 of locals (ties -> lower index, matching lax.top_k)
  int i1 = 0; float v1 = we[2];
#pragma unroll
  for (int n = 1; n < 6; ++n) if (we[2 + n] > v1) { v1 = we[2 + n]; i1 = n; }
  int i2 = -1; float v2 = -1e30f;
#pragma unroll
  for (int n = 0; n < 6; ++n) if (n != i1 && we[2 + n] > v2) { v2 = we[2 + n]; i2 = n; }
  float ow[8];
  ow[0] = we[0]; ow[1] = we[1];
#pragma unroll
  for (int n = 0; n < 6; ++n) ow[2 + n] = 0.f;
  ow[2 + i1] = v1; ow[2 + i2] = v2;
  float* wp = wtok + (size_t)t * 8;
#pragma unroll
  for (int e = 0; e < 8; ++e) wp[e] = ow[e];
  __shared__ float red[256];
  red[threadIdx.x] = ent;
  __syncthreads();
  for (int s = 128; s > 0; s >>= 1) {
    if (threadIdx.x < s) red[threadIdx.x] += red[threadIdx.x + s];
    __syncthreads();
  }
  if (threadIdx.x == 0) atomicAdd(entp, red[0]);
}

// ---------------------------------------------------------------------------
// small helper kernels
// ---------------------------------------------------------------------------
__global__ void zero_kernel(float* p) { p[0] = 0.f; }

__global__ void convert_x_kernel(const float* __restrict__ x,
                                 __hip_bfloat16* __restrict__ xb,
                                 __hip_bfloat16* __restrict__ xlo, int n4) {
  int stride = gridDim.x * blockDim.x;
  for (int i = blockIdx.x * blockDim.x + threadIdx.x; i < n4; i += stride) {
    float4 v = ((const float4*)x)[i];
    float vv[4] = {v.x, v.y, v.z, v.w};
    union { __hip_bfloat16 h[4]; ushort4 u; } hi, lo;
#pragma unroll
    for (int j = 0; j < 4; ++j) {
      hi.h[j] = __float2bfloat16(vv[j]);
      lo.h[j] = __float2bfloat16(vv[j] - __bfloat162float(hi.h[j]));
    }
    ((ushort4*)xb)[i] = hi.u;
    ((ushort4*)xlo)[i] = lo.u;
  }
}

// router W1 -> [N=512][K=768] bf16: cols 0..255 = W_hi, 256..511 = W_hi, 512..767 = W_lo
__global__ void build_router_w_kernel(const float* __restrict__ rw1,
                                      __hip_bfloat16* __restrict__ dst) {
  int i = blockIdx.x * 256 + threadIdx.x;   // 512*768 total
  int n = i / 768, k = i - n * 768;
  float src = rw1[(size_t)(k & 255) * 512 + n];
  __hip_bfloat16 hv = __float2bfloat16(src);
  dst[i] = (k < 512) ? hv : __float2bfloat16(src - __bfloat162float(hv));
}

// biasA[2048] = [gb1_0|gb1_1|lb1_0|lb1_1]; biasB[2048] = [lb1_2..lb1_5];
// Ball[8][256] = [gb3_0;gb3_1;lb2_0..5]
__global__ void build_biases_kernel(const float* __restrict__ gb1, const float* __restrict__ lb1,
                                    const float* __restrict__ gb3, const float* __restrict__ lb2,
                                    float* __restrict__ biasA, float* __restrict__ biasB,
                                    float* __restrict__ Ball) {
  int i = blockIdx.x * 256 + threadIdx.x;   // 6144 total
  if (i < 2048) {
    biasA[i] = (i < 1024) ? gb1[i] : lb1[i - 1024];
  } else if (i < 4096) {
    int j = i - 2048;
    biasB[j] = lb1[1024 + j];
  } else {
    int j = i - 4096;
    Ball[j] = (j < 512) ? gb3[j] : lb2[j - 512];
  }
}

struct ConvDesc { const float* src; __hip_bfloat16* dst; int K; int N; int ldb; int koff; };
struct ConvArgs { ConvDesc d[20]; };

// dst[n*ldb + koff + k] = bf16(src[k*N+n]) : weight transpose+convert
__global__ void convert_wt_kernel(ConvArgs a) {
  ConvDesc c = a.d[blockIdx.y];
  int total = c.K * c.N;
  int stride = gridDim.x * blockDim.x;
  for (int e = blockIdx.x * blockDim.x + threadIdx.x; e < total; e += stride) {
    int n = e / c.K;
    int k = e - n * c.K;
    c.dst[(size_t)n * c.ldb + c.koff + k] = __float2bfloat16(c.src[(size_t)k * c.N + n]);
  }
}

// meanz[r][o] = mean_c pred[r*512+c][o], r = s*32+b
__global__ void mean_kernel(const float* __restrict__ pred, float* __restrict__ meanz) {
  int r = blockIdx.x, o = threadIdx.x;
  const float* p = pred + (size_t)r * 512 * 256 + o;
  float s0 = 0.f, s1 = 0.f, s2 = 0.f, s3 = 0.f;
  for (int c = 0; c < 512; c += 4) {
    s0 += p[(size_t)(c + 0) * 256]; s1 += p[(size_t)(c + 1) * 256];
    s2 += p[(size_t)(c + 2) * 256]; s3 += p[(size_t)(c + 3) * 256];
  }
  meanz[r * 256 + o] = (s0 + s1 + s2 + s3) * (1.0f / 512.0f);
}

__global__ void te_kernel(const float* __restrict__ meanz, const float* __restrict__ tw,
                          const float* __restrict__ tb, float* __restrict__ reprs) {
  __shared__ float row[256];
  int r = blockIdx.x, j = threadIdx.x;
  row[j] = meanz[r * 256 + j];
  __syncthreads();
  float a = 0.f;
  for (int k = 0; k < 256; ++k) a += row[k] * tw[k * 256 + j];
  reprs[r * 256 + j] = gelu_f(a + tb[j]);
}

__global__ void wc_kernel(const float* __restrict__ reprs, const float* __restrict__ wmem,
                          const float* __restrict__ wcw, const float* __restrict__ wcb,
                          float* __restrict__ sw) {
  __shared__ float red[128][3];
  int b = blockIdx.x, tid = threadIdx.x;
  float a0 = 0.f, a1 = 0.f, a2 = 0.f;
  for (int i = tid; i < 771; i += 128) {
    float cv = (i < 768) ? reprs[(i >> 8) * 8192 + b * 256 + (i & 255)] : wmem[i - 768];
    a0 += cv * wcw[i * 3 + 0]; a1 += cv * wcw[i * 3 + 1]; a2 += cv * wcw[i * 3 + 2];
  }
  red[tid][0] = a0; red[tid][1] = a1; red[tid][2] = a2;
  __syncthreads();
  for (int s = 64; s > 0; s >>= 1) {
    if (tid < s) {
      red[tid][0] += red[tid + s][0];
      red[tid][1] += red[tid + s][1];
      red[tid][2] += red[tid + s][2];
    }
    __syncthreads();
  }
  if (tid == 0) {
    float r[3]; float mx = -1e30f;
    for (int j = 0; j < 3; ++j) {
      float v = tanhf(red[0][j] + wcb[j]);
      r[j] = log1pf(expf(v));
      mx = fmaxf(mx, r[j]);
    }
    float s = 0.f;
    for (int j = 0; j < 3; ++j) { r[j] = expf(r[j] - mx); s += r[j]; }
    for (int j = 0; j < 3; ++j) sw[b * 3 + j] = r[j] / s;
  }
}

__global__ void weighted_kernel(const float* __restrict__ pred, const float* __restrict__ sw,
                                __hip_bfloat16* __restrict__ wb) {
  int t = blockIdx.x, o = threadIdx.x;
  int b = t >> 9;
  float s0 = sw[b * 3 + 0], s1 = sw[b * 3 + 1], s2 = sw[b * 3 + 2];
  size_t i = (size_t)t * 256 + o;
  float v = pred[i] * s0 + pred[i + (size_t)TBC_ * 256] * s1 + pred[i + (size_t)2 * TBC_ * 256] * s2;
  wb[i] = __float2bfloat16(v);
}

__global__ void finalize_kernel(const float* __restrict__ entp, float* __restrict__ out) {
  out[4194304] = -0.1f * entp[0] / 49152.0f;
}

// ---------------------------------------------------------------------------
extern "C" void kernel_launch(void* const* d_in, const int* in_sizes, int n_in,
                              void* d_out, int out_size, void* d_ws, size_t ws_size,
                              hipStream_t stream) {
  const float* x    = (const float*)d_in[0];
  const float* rw1  = (const float*)d_in[1];
  const float* rb1  = (const float*)d_in[2];
  const float* rw2  = (const float*)d_in[3];
  const float* rb2  = (const float*)d_in[4];
  const float* gW1  = (const float*)d_in[5];
  const float* gb1  = (const float*)d_in[6];
  const float* gW2  = (const float*)d_in[7];
  const float* gb2  = (const float*)d_in[8];
  const float* gW3  = (const float*)d_in[9];
  const float* gb3  = (const float*)d_in[10];
  const float* lW1  = (const float*)d_in[11];
  const float* lb1  = (const float*)d_in[12];
  const float* lW2  = (const float*)d_in[13];
  const float* lb2  = (const float*)d_in[14];
  const float* tew  = (const float*)d_in[15];
  const float* teb  = (const float*)d_in[16];
  const float* wmem = (const float*)d_in[17];
  const float* wcw  = (const float*)d_in[18];
  const float* wcb  = (const float*)d_in[19];
  const float* ow1  = (const float*)d_in[20];
  const float* ob1  = (const float*)d_in[21];
  const float* ow2  = (const float*)d_in[22];
  const float* ob2  = (const float*)d_in[23];
  float* out = (float*)d_out;

  char* ws = (char*)d_ws;
  size_t off = 0;
  auto alloc = [&](size_t bytes) -> void* {
    void* p = ws + off;
    off = (off + bytes + 255) & ~(size_t)255;
    return p;
  };

  const bool batched = (ws_size >= (440ull << 20));

  // ---- common small buffers ----
  __hip_bfloat16* Xb   = (__hip_bfloat16*)alloc((size_t)T_ * E_ * 2);
  __hip_bfloat16* Xlo  = (__hip_bfloat16*)alloc((size_t)T_ * E_ * 2);
  __hip_bfloat16* rW1s = (__hip_bfloat16*)alloc(512ull * 768 * 2);
  float* wtok  = (float*)alloc((size_t)T_ * 8 * 4);
  float* entp  = (float*)alloc(256);
  float* meanz = (float*)alloc(96ull * 256 * 4);
  float* reprs = (float*)alloc(96ull * 256 * 4);
  float* swp   = (float*)alloc(512);
  __hip_bfloat16* ow1t = (__hip_bfloat16*)alloc((size_t)P_ * E_ * 2);
  __hip_bfloat16* ow2t = (__hip_bfloat16*)alloc((size_t)P_ * P_ * 2);

  zero_kernel<<<1, 1, 0, stream>>>(entp);
  convert_x_kernel<<<1024, 256, 0, stream>>>(x, Xb, Xlo, T_ * E_ / 4);
  build_router_w_kernel<<<1536, 256, 0, stream>>>(rw1, rW1s);

  if (batched) {
    // ---- batched path (~410 MiB) ----
    __hip_bfloat16* Bt1a = (__hip_bfloat16*)alloc(2048ull * 256 * 2);
    __hip_bfloat16* Bt1b = (__hip_bfloat16*)alloc(2048ull * 256 * 2);
    __hip_bfloat16* gW2t = (__hip_bfloat16*)alloc(2ull * H_ * H_ * 2);
    __hip_bfloat16* Bf1  = (__hip_bfloat16*)alloc(256ull * 2048 * 2);
    __hip_bfloat16* Bf2  = (__hip_bfloat16*)alloc(256ull * 2048 * 2);
    float* biasA = (float*)alloc(2048 * 4);
    float* biasB = (float*)alloc(2048 * 4);
    float* Ball  = (float*)alloc(2048 * 4);
    __hip_bfloat16* Ap = (__hip_bfloat16*)alloc((size_t)T_ * 2048 * 2);  // A' [T,2048], reused grp1/grp2
    __hip_bfloat16* G  = (__hip_bfloat16*)alloc((size_t)T_ * 1024 * 2);  // gh1 [T,1024]
    float* pred = (float*)alloc((size_t)T_ * P_ * 4);
    // aliases: Hr (router hidden fp32 [T,512] = 100.7MB) in A' (201MB) — dead before A' writes.
    float* Hr = (float*)Ap;
    // out-head buffers alias Xlo (25MB, dead after router GEMM)
    __hip_bfloat16* wghtB = Xlo;
    __hip_bfloat16* out1B = Xlo + (size_t)TBC_ * 256;

    ConvArgs ca;
    int d = 0;
    // Bt1a: [gW1_0|gW1_1|lW1_0|lW1_1]^T blocks, each [512 rows,256]
    for (int s = 0; s < 2; ++s) ca.d[d++] = { gW1 + (size_t)s * E_ * H_, Bt1a + (size_t)s * 512 * 256, E_, H_, 256, 0 };
    for (int n = 0; n < 2; ++n) ca.d[d++] = { lW1 + (size_t)n * E_ * H_, Bt1a + (size_t)(2 + n) * 512 * 256, E_, H_, 256, 0 };
    // Bt1b: [lW1_2..5]^T
    for (int n = 2; n < 6; ++n) ca.d[d++] = { lW1 + (size_t)n * E_ * H_, Bt1b + (size_t)(n - 2) * 512 * 256, E_, H_, 256, 0 };
    // gW2t
    for (int s = 0; s < 2; ++s) ca.d[d++] = { gW2 + (size_t)s * H_ * H_, gW2t + (size_t)s * H_ * H_, H_, H_, 512, 0 };
    // Bf1 [256 rows, 2048]: K-segs {gW3_0, gW3_1, lW2_0, lW2_1}
    for (int s = 0; s < 2; ++s) ca.d[d++] = { gW3 + (size_t)s * H_ * P_, Bf1, H_, P_, 2048, s * 512 };
    for (int n = 0; n < 2; ++n) ca.d[d++] = { lW2 + (size_t)n * H_ * P_, Bf1, H_, P_, 2048, (2 + n) * 512 };
    // Bf2: K-segs {lW2_2..5}
    for (int n = 2; n < 6; ++n) ca.d[d++] = { lW2 + (size_t)n * H_ * P_, Bf2, H_, P_, 2048, (n - 2) * 512 };
    // out-head
    ca.d[d++] = { ow1, ow1t, E_, P_, 256, 0 };
    ca.d[d++] = { ow2, ow2t, P_, P_, 256, 0 };
    convert_wt_kernel<<<dim3(64, d), 256, 0, stream>>>(ca);
    build_biases_kernel<<<24, 256, 0, stream>>>(gb1, lb1, gb3, lb2, biasA, biasB, Ball);

    // router
    gemm_bf16_k<3, true, true><<<dim3(T_ / 128, 4), 256, 0, stream>>>(
        Xb, rW1s, rb1, Hr, nullptr, T_, 512, 768, 0, Xlo, 256, 768, 512, nullptr, nullptr);
    logits_kernel<<<T_ / 256, 256, 0, stream>>>(Hr, rw2, rb2, wtok, entp);

    // group 1: L1 for {g0,g1,l0,l1}: gh1 -> G, scaled lh -> A'[*,1024..2047]
    gemm_bf16_k<7, true, false><<<dim3(T_ / 128, 16), 256, 0, stream>>>(
        Xb, Bt1a, biasA, Ap, wtok, T_, 2048, 256, 0, nullptr, 256, 256, 2048, G, nullptr);
    // L2 global s=0,1: scaled gh2 -> A'[*, s*512..]
    for (int s = 0; s < 2; ++s)
      gemm_bf16_k<4, true, false><<<dim3(T_ / 128, 4), 256, 0, stream>>>(
          G + (size_t)s * 512, gW2t + (size_t)s * H_ * H_, gb2 + s * H_,
          Ap + (size_t)s * 512, wtok, T_, 512, 512, s, nullptr, 1024, 512, 2048, nullptr, nullptr);
    // final #1: pred = A' @ Bf1 + sum_e w*b_e
    gemm_bf16_k<6, true, false><<<dim3(T_ / 128, 2), 256, 0, stream>>>(
        Ap, Bf1, nullptr, pred, wtok, T_, 256, 2048, 0, nullptr, 2048, 2048, 256, nullptr, Ball);
    // group 2: L1 for {l2..l5}: scaled lh -> A'[*,0..2047]
    gemm_bf16_k<4, true, false><<<dim3(T_ / 128, 16), 256, 0, stream>>>(
        Xb, Bt1b, biasB, Ap, wtok, T_, 2048, 256, 4, nullptr, 256, 256, 2048, nullptr, nullptr);
    // final #2: pred += A' @ Bf2
    gemm_bf16_k<6, false, false><<<dim3(T_ / 128, 2), 256, 0, stream>>>(
        Ap, Bf2, nullptr, pred, wtok, T_, 256, 2048, 0, nullptr, 2048, 2048, 256, nullptr, nullptr);

    mean_kernel<<<96, 256, 0, stream>>>(pred, meanz);
    te_kernel<<<96, 256, 0, stream>>>(meanz, tew, teb, reprs);
    wc_kernel<<<32, 128, 0, stream>>>(reprs, wmem, wcw, wcb, swp);
    weighted_kernel<<<TBC_, 256, 0, stream>>>(pred, swp, wghtB);

    gemm_bf16_k<0, true, false><<<dim3(TBC_ / 128, 2), 256, 0, stream>>>(
        wghtB, ow1t, ob1, out1B, nullptr, TBC_, 256, 256, 0, nullptr, 256, 256, 256, nullptr, nullptr);
    gemm_bf16_k<2, true, false><<<dim3(TBC_ / 128, 2), 256, 0, stream>>>(
        out1B, ow2t, ob2, out, nullptr, TBC_, 256, 256, 0, nullptr, 256, 256, 256, nullptr, nullptr);
  } else {
    // ---- serial fallback (Round-3 proven, ~206 MiB) ----
    __hip_bfloat16* gW1t = (__hip_bfloat16*)alloc(2ull * H_ * E_ * 2);
    __hip_bfloat16* gW2t = (__hip_bfloat16*)alloc(2ull * H_ * H_ * 2);
    __hip_bfloat16* gW3t = (__hip_bfloat16*)alloc(2ull * P_ * H_ * 2);
    __hip_bfloat16* lW1t = (__hip_bfloat16*)alloc(6ull * H_ * E_ * 2);
    __hip_bfloat16* lW2t = (__hip_bfloat16*)alloc(6ull * P_ * H_ * 2);
    __hip_bfloat16* bufA = (__hip_bfloat16*)alloc((size_t)T_ * H_ * 2);
    __hip_bfloat16* bufB = (__hip_bfloat16*)alloc((size_t)T_ * H_ * 2);
    float* pred = (float*)alloc((size_t)T_ * P_ * 4);
    float* Hr = (float*)bufB;   // alias
    __hip_bfloat16* wghtB = bufA;
    __hip_bfloat16* out1B = bufB;

    ConvArgs ca;
    int d = 0;
    for (int s = 0; s < 2; ++s) ca.d[d++] = { gW1 + (size_t)s * E_ * H_, gW1t + (size_t)s * H_ * E_, E_, H_, 256, 0 };
    for (int s = 0; s < 2; ++s) ca.d[d++] = { gW2 + (size_t)s * H_ * H_, gW2t + (size_t)s * H_ * H_, H_, H_, 512, 0 };
    for (int s = 0; s < 2; ++s) ca.d[d++] = { gW3 + (size_t)s * H_ * P_, gW3t + (size_t)s * P_ * H_, H_, P_, 512, 0 };
    for (int n = 0; n < 6; ++n) ca.d[d++] = { lW1 + (size_t)n * E_ * H_, lW1t + (size_t)n * H_ * E_, E_, H_, 256, 0 };
    for (int n = 0; n < 6; ++n) ca.d[d++] = { lW2 + (size_t)n * H_ * P_, lW2t + (size_t)n * P_ * H_, H_, P_, 512, 0 };
    ca.d[d++] = { ow1, ow1t, E_, P_, 256, 0 };
    ca.d[d++] = { ow2, ow2t, P_, P_, 256, 0 };
    convert_wt_kernel<<<dim3(64, d), 256, 0, stream>>>(ca);

    gemm_bf16_k<3, true, true><<<dim3(T_ / 128, 4), 256, 0, stream>>>(
        Xb, rW1s, rb1, Hr, nullptr, T_, 512, 768, 0, Xlo, 256, 768, 512, nullptr, nullptr);
    logits_kernel<<<T_ / 256, 256, 0, stream>>>(Hr, rw2, rb2, wtok, entp);

    for (int s = 0; s < 2; ++s) {
      gemm_bf16_k<0, true, false><<<dim3(T_ / 128, 4), 256, 0, stream>>>(
          Xb, gW1t + (size_t)s * H_ * E_, gb1 + s * H_, bufA, nullptr, T_, 512, 256, 0, nullptr, 256, 256, 512, nullptr, nullptr);
      gemm_bf16_k<0, true, false><<<dim3(T_ / 128, 4), 256, 0, stream>>>(
          bufA, gW2t + (size_t)s * H_ * H_, gb2 + s * H_, bufB, nullptr, T_, 512, 512, 0, nullptr, 512, 512, 512, nullptr, nullptr);
      if (s == 0)
        gemm_bf16_k<1, true, false><<<dim3(T_ / 128, 2), 256, 0, stream>>>(
            bufB, gW3t + (size_t)s * P_ * H_, gb3 + s * P_, pred, wtok, T_, 256, 512, s, nullptr, 512, 512, 256, nullptr, nullptr);
      else
        gemm_bf16_k<1, false, false><<<dim3(T_ / 128, 2), 256, 0, stream>>>(
            bufB, gW3t + (size_t)s * P_ * H_, gb3 + s * P_, pred, wtok, T_, 256, 512, s, nullptr, 512, 512, 256, nullptr, nullptr);
    }
    for (int n = 0; n < 6; ++n) {
      gemm_bf16_k<0, true, false><<<dim3(T_ / 128, 4), 256, 0, stream>>>(
          Xb, lW1t + (size_t)n * H_ * E_, lb1 + n * H_, bufA, nullptr, T_, 512, 256, 0, nullptr, 256, 256, 512, nullptr, nullptr);
      gemm_bf16_k<1, false, false><<<dim3(T_ / 128, 2), 256, 0, stream>>>(
          bufA, lW2t + (size_t)n * P_ * H_, lb2 + n * P_, pred, wtok, T_, 256, 512, 2 + n, nullptr, 512, 512, 256, nullptr, nullptr);
    }

    mean_kernel<<<96, 256, 0, stream>>>(pred, meanz);
    te_kernel<<<96, 256, 0, stream>>>(meanz, tew, teb, reprs);
    wc_kernel<<<32, 128, 0, stream>>>(reprs, wmem, wcw, wcb, swp);
    weighted_kernel<<<TBC_, 256, 0, stream>>>(pred, swp, wghtB);

    gemm_bf16_k<0, true, false><<<dim3(TBC_ / 128, 2), 256, 0, stream>>>(
        wghtB, ow1t, ob1, out1B, nullptr, TBC_, 256, 256, 0, nullptr, 256, 256, 256, nullptr, nullptr);
    gemm_bf16_k<2, true, false><<<dim3(TBC_ / 128, 2), 256, 0, stream>>>(
        out1B, ow2t, ob2, out, nullptr, TBC_, 256, 256, 0, nullptr, 256, 256, 256, nullptr, nullptr);
  }

  finalize_kernel<<<1, 1, 0, stream>>>(entp, out);
  (void)in_sizes; (void)n_in; (void)out_size;
}